// Round 1
// baseline (73.735 us; speedup 1.0000x reference)
//
#include <hip/hip_runtime.h>

#define CCH 3
#define KK 16
#define HW (1024 * 1024)

__global__ __launch_bounds__(256) void pixelwise_kernel(
    const float* __restrict__ x,
    const float* __restrict__ M,
    const float* __restrict__ p_a,
    const float* __restrict__ p_t,
    const float* __restrict__ bias_c,
    const float* __restrict__ bias,
    float* __restrict__ out)
{
    // Uniform parameters — all addresses are wave-uniform, compiler emits s_loads.
    float rs[CCH];
#pragma unroll
    for (int c = 0; c < CCH; ++c)
        rs[c] = M[c * 3 + 0] + M[c * 3 + 1] + M[c * 3 + 2];

    float pa[CCH][KK];
    float bb[CCH][KK];  // bias_c[c] - p_t[c][k], folded offset
#pragma unroll
    for (int c = 0; c < CCH; ++c) {
#pragma unroll
        for (int k = 0; k < KK; ++k) {
            pa[c][k] = p_a[c * KK + k];
            bb[c][k] = bias_c[c] - p_t[c * KK + k];
        }
    }
    const float b0 = bias[0];

    const int idx  = blockIdx.x * blockDim.x + threadIdx.x;
    const int base = idx * 4;
    if (base >= HW) return;

    const float4 x0 = *(const float4*)(x + 0 * HW + base);
    const float4 x1 = *(const float4*)(x + 1 * HW + base);
    const float4 x2 = *(const float4*)(x + 2 * HW + base);

    float a0 = b0, a1 = b0, a2 = b0, a3 = b0;

#pragma unroll
    for (int c = 0; c < CCH; ++c) {
        const float4 xv = (c == 0) ? x0 : (c == 1) ? x1 : x2;
        const float s0 = xv.x * rs[c];
        const float s1 = xv.y * rs[c];
        const float s2 = xv.z * rs[c];
        const float s3 = xv.w * rs[c];
#pragma unroll
        for (int k = 0; k < KK; ++k) {
            const float t0 = fmaxf(s0 + bb[c][k], 0.0f);
            const float t1 = fmaxf(s1 + bb[c][k], 0.0f);
            const float t2 = fmaxf(s2 + bb[c][k], 0.0f);
            const float t3 = fmaxf(s3 + bb[c][k], 0.0f);
            a0 = fmaf(pa[c][k], t0, a0);
            a1 = fmaf(pa[c][k], t1, a1);
            a2 = fmaf(pa[c][k], t2, a2);
            a3 = fmaf(pa[c][k], t3, a3);
        }
    }

    *(float4*)(out + base) = make_float4(a0, a1, a2, a3);
}

extern "C" void kernel_launch(void* const* d_in, const int* in_sizes, int n_in,
                              void* d_out, int out_size, void* d_ws, size_t ws_size,
                              hipStream_t stream)
{
    const float* x      = (const float*)d_in[0];
    const float* M      = (const float*)d_in[1];
    const float* p_a    = (const float*)d_in[2];
    const float* p_t    = (const float*)d_in[3];
    const float* bias_c = (const float*)d_in[4];
    const float* bias   = (const float*)d_in[5];
    float* out = (float*)d_out;

    const int threads = 256;
    const int groups  = HW / 4;            // one float4 per thread
    const int blocks  = groups / threads;  // 1024
    pixelwise_kernel<<<blocks, threads, 0, stream>>>(x, M, p_a, p_t, bias_c, bias, out);
}